// Round 2
// baseline (542.997 us; speedup 1.0000x reference)
//
#include <hip/hip_runtime.h>
#include <hip/hip_bf16.h>
#include <cstdint>

// B=16, D=8, S=256, L=512, BD=128, M=32768, F=1536
// d_out = [output: 16*2048*512] ++ [output_matrix_attn: 16*2048*2048], fp32.
//
// Fragment-major layouts (16x16x32 bf16 MFMA, lane l, elem j):
//   A-type frag: X[m = tile*16 + (l&15)][k = kchunk*32 + (l>>4)*8 + j]
//   qb[bd][mtile16][kchunk16][512], kb[bd][ttile16][kchunk16][512],
//   vb[bd][ntile32][tchunk8][512]  (V stored transposed: lane&15 = n, elems = t)

typedef unsigned short u16;
typedef short bf16x8 __attribute__((ext_vector_type(8)));
typedef float f32x4 __attribute__((ext_vector_type(4)));

__device__ __forceinline__ u16 f2bf(float f) {
    union { float f; unsigned int u; } v; v.f = f;
    unsigned int r = v.u + 0x7FFF + ((v.u >> 16) & 1);
    return (u16)(r >> 16);
}

__device__ __forceinline__ void gload16(const u16* g, u16* l) {
    __builtin_amdgcn_global_load_lds(
        (const __attribute__((address_space(1))) unsigned int*)g,
        (__attribute__((address_space(3))) unsigned int*)l, 16, 0, 0);
}

__device__ __forceinline__ f32x4 mfma16(bf16x8 a, bf16x8 b, f32x4 c) {
    return __builtin_amdgcn_mfma_f32_16x16x32_bf16(a, b, c, 0, 0, 0);
}

// ---------------------------------------------------------------------------
// Kernel 0: fp32 -> bf16 cast of x and Wqkv. NT loads (one-shot stream).
// ---------------------------------------------------------------------------
__global__ __launch_bounds__(256) void cast_bf16(const float* __restrict__ x,
                                                 const float* __restrict__ w,
                                                 u16* __restrict__ xb,
                                                 u16* __restrict__ wb) {
    const size_t NX = 16777216 / 8, NW = 786432 / 8;
    size_t i = (size_t)blockIdx.x * 256 + threadIdx.x;
    const float* src; u16* dst; size_t e;
    if (i < NX)            { src = x; dst = xb; e = i; }
    else if (i < NX + NW)  { src = w; dst = wb; e = i - NX; }
    else return;
    const f32x4 a = __builtin_nontemporal_load((const f32x4*)&src[e * 8]);
    const f32x4 b = __builtin_nontemporal_load((const f32x4*)&src[e * 8 + 4]);
    u16 o[8] = { f2bf(a[0]), f2bf(a[1]), f2bf(a[2]), f2bf(a[3]),
                 f2bf(b[0]), f2bf(b[1]), f2bf(b[2]), f2bf(b[3]) };
    *(uint4*)&dst[e * 8] = *(const uint4*)o;
}

// ---------------------------------------------------------------------------
// Kernel 1: QKV projection, bf16 MFMA, fragment-major epilogue.
// Block 128m x 256f, BK=32, 4 waves, wave = 64m x 128f.
// Flat grid 1536 with bijective XCD swizzle: the 6 f-blocks sharing one
// A-panel land on the SAME XCD L2 (A HBM traffic 192MB -> 32MB).
// Epilogue stores are NT: qb/kb/vb are consumed much later (by attn), so
// don't evict the A-panels qkv itself is reusing.
// ---------------------------------------------------------------------------
__global__ __launch_bounds__(256, 2) void qkv_gemm(const u16* __restrict__ xb,
                                                   const u16* __restrict__ wb,
                                                   const float* __restrict__ bias,
                                                   u16* __restrict__ qb,
                                                   u16* __restrict__ kb,
                                                   u16* __restrict__ vb) {
    __shared__ __align__(16) u16 sA[8 * 512];    // 8 m-tiles (also epilogue patch)
    __shared__ __align__(16) u16 sB[16 * 512];   // 16 f-tiles
    const int tid = threadIdx.x, lane = tid & 63, w = tid >> 6;
    const int lr = lane & 15, lh = lane >> 4;
    const int bfl = blockIdx.x;
    const int work = (bfl & 7) * 192 + (bfl >> 3);
    const int mb = work / 6;
    const int fb = work - mb * 6;
    const int f0 = fb * 256, m0 = mb * 128;
    const int wm = w & 1, wf = w >> 1;

    f32x4 acc[4][8];
#pragma unroll
    for (int i = 0; i < 4; ++i)
#pragma unroll
        for (int j = 0; j < 8; ++j) acc[i][j] = (f32x4){0.f, 0.f, 0.f, 0.f};

#pragma unroll 1
    for (int k0 = 0; k0 < 512; k0 += 32) {
#pragma unroll
        for (int i = 0; i < 6; ++i) {            // 24 staging jobs, 6 per wave
            const int j = w * 6 + i;
            if (j < 8) {
                gload16(xb + (size_t)(m0 + j * 16 + lr) * 512 + k0 + lh * 8,
                        &sA[j * 512]);
            } else {
                const int jb = j - 8;
                gload16(wb + (size_t)(f0 + jb * 16 + lr) * 512 + k0 + lh * 8,
                        &sB[jb * 512]);
            }
        }
        __syncthreads();
        bf16x8 af[4], bf[8];
#pragma unroll
        for (int mt = 0; mt < 4; ++mt)
            af[mt] = *(const bf16x8*)&sA[(wm * 4 + mt) * 512 + lane * 8];
#pragma unroll
        for (int ft = 0; ft < 8; ++ft)
            bf[ft] = *(const bf16x8*)&sB[(wf * 8 + ft) * 512 + lane * 8];
#pragma unroll
        for (int mt = 0; mt < 4; ++mt)
#pragma unroll
            for (int ft = 0; ft < 8; ++ft)
                acc[mt][ft] = mfma16(af[mt], bf[ft], acc[mt][ft]);
        __syncthreads();
    }

    // ---- Epilogue: LDS bounce C-layout -> fragment-major, 16B NT stores ----
    u16* patch = &sA[w * 1024];     // 2 KB per wave; patch row stride 40 u16
    const int bdq = m0 >> 8;
    float bv[8];
#pragma unroll
    for (int ft = 0; ft < 8; ++ft) bv[ft] = bias[f0 + wf * 128 + ft * 16 + lr];

    if (f0 < 1024) {
        u16* dstb = (f0 < 512) ? qb : kb;
        const int mtileg = ((m0 & 255) >> 4) + wm * 4;
        const int kbase = ((f0 & 511) + wf * 128) >> 5;
#pragma unroll
        for (int mt = 0; mt < 4; ++mt)
#pragma unroll
            for (int ftp = 0; ftp < 4; ++ftp) {
#pragma unroll
                for (int h = 0; h < 2; ++h) {
                    const int ft = ftp * 2 + h;
                    const f32x4 a = acc[mt][ft];
#pragma unroll
                    for (int r = 0; r < 4; ++r)
                        patch[(lh * 4 + r) * 40 + h * 16 + lr] = f2bf(a[r] + bv[ft]);
                }
                asm volatile("s_waitcnt lgkmcnt(0)" ::: "memory");
                bf16x8 frag = *(const bf16x8*)&patch[lr * 40 + lh * 8];
                u16* dst = dstb +
                    ((size_t)(bdq * 16 + mtileg + mt) * 16 + (kbase + ftp)) * 512 +
                    lane * 8;
                __builtin_nontemporal_store(frag, (bf16x8*)dst);
            }
    } else {
        const int nbase = ((f0 - 1024) >> 4) + wf * 8;
        const int tbase = ((m0 & 255) >> 5) + wm * 2;
#pragma unroll
        for (int ft = 0; ft < 8; ++ft)
#pragma unroll
            for (int mtp = 0; mtp < 2; ++mtp) {
#pragma unroll
                for (int h = 0; h < 2; ++h) {
                    const f32x4 a = acc[mtp * 2 + h][ft];
#pragma unroll
                    for (int r = 0; r < 4; ++r)
                        patch[lr * 40 + h * 16 + lh * 4 + r] = f2bf(a[r] + bv[ft]);
                }
                asm volatile("s_waitcnt lgkmcnt(0)" ::: "memory");
                bf16x8 frag = *(const bf16x8*)&patch[lr * 40 + lh * 8];
                u16* dst = vb +
                    ((size_t)(bdq * 32 + nbase + ft) * 8 + (tbase + mtp)) * 512 +
                    lane * 8;
                __builtin_nontemporal_store(frag, (bf16x8*)dst);
            }
    }
}

// ---------------------------------------------------------------------------
// Kernel 2: attention. Flat grid 512 (64 q-rows x bd), XCD-swizzled so the
// 4 r0-blocks of one bd share an XCD (K/V = 512 KB per bd, L2-resident).
// NO LDS staging of Q/K/V: fragment-major layouts are loaded directly from
// global (bf16x8 @ base+lane*16B, fully coalesced) -> phases 1 and 3 are
// barrier-free; L2 absorbs the 2x per-block read amplification.
// All streamed output (zero-fill, diag, out) uses NT stores to keep L2
// clean for the K/V/Q working set.
// ---------------------------------------------------------------------------
__global__ __launch_bounds__(256, 2) void attn_kernel(const u16* __restrict__ qb,
                                                      const u16* __restrict__ kb,
                                                      const u16* __restrict__ vb,
                                                      const int* __restrict__ n_ptr,
                                                      float* __restrict__ out,
                                                      float* __restrict__ outmat) {
    __shared__ __align__(16) u16 sP[8 * 4 * 512];   // 32 KB frag-major P
    __shared__ float sStat[64][2];

    const int tid = threadIdx.x, lane = tid & 63, w = tid >> 6;
    const int lr = lane & 15, lh = lane >> 4;
    // XCD swizzle: 512 blocks, 64 per XCD = 16 bds x 4 r-blocks.
    const int bfl = blockIdx.x;
    const int work = (bfl & 7) * 64 + (bfl >> 3);
    const int bd = work >> 2, rblk = work & 3;
    const int r0 = rblk * 64;
    const int n = *n_ptr;
    const int wm = w & 1, wt = w >> 1;
    const int b_ = bd >> 3, dd = bd & 7;
    float* zbase = &outmat[(size_t)b_ * 4194304 + (size_t)(dd * 256 + r0) * 2048];

    f32x4 acc[2][8];
#pragma unroll
    for (int i = 0; i < 2; ++i)
#pragma unroll
        for (int j = 0; j < 8; ++j) acc[i][j] = (f32x4){0.f, 0.f, 0.f, 0.f};

    // ---------------- Phase 1: scores = Q K^T (barrier-free) ----------------
    // Direct fragment loads: af[mt] <- qb tile (rblk*4 + wm*2 + mt), chunk kc
    //                        bfr[jt] <- kb tile (wt*8 + jt), chunk kc
    const u16* qbase = qb + ((size_t)(bd * 16 + rblk * 4 + wm * 2) * 16) * 512 + lane * 8;
    const u16* kbase = kb + ((size_t)(bd * 16 + wt * 8) * 16) * 512 + lane * 8;

#pragma unroll 2
    for (int kc = 0; kc < 16; ++kc) {
        bf16x8 af[2], bfr[8];
#pragma unroll
        for (int mt = 0; mt < 2; ++mt)
            af[mt] = *(const bf16x8*)(qbase + (size_t)(mt * 16 + kc) * 512);
#pragma unroll
        for (int jt = 0; jt < 8; ++jt)
            bfr[jt] = *(const bf16x8*)(kbase + (size_t)(jt * 16 + kc) * 512);
        // interleaved zero-fill of outmat rows: 8 NT float4 stores/thread/step
#pragma unroll
        for (int u = 0; u < 8; ++u) {
            const int idx = (kc * 8 + u) * 256 + tid;   // covers 64*512 slots
            const f32x4 z = (f32x4){0.f, 0.f, 0.f, 0.f};
            __builtin_nontemporal_store(
                z, (f32x4*)&zbase[(size_t)(idx >> 9) * 2048 + (idx & 511) * 4]);
        }
#pragma unroll
        for (int mt = 0; mt < 2; ++mt)
#pragma unroll
            for (int jt = 0; jt < 8; ++jt)
                acc[mt][jt] = mfma16(af[mt], bfr[jt], acc[mt][jt]);
    }

    // ---------------- Phase 2: softmax + mask ----------------
    const float scale = 0.044194173824159216f;
#pragma unroll
    for (int i = 0; i < 2; ++i)
#pragma unroll
        for (int j = 0; j < 8; ++j) acc[i][j] *= scale;

    float rmax[2][4], rinv[2][4];
#pragma unroll
    for (int i = 0; i < 2; ++i)
#pragma unroll
        for (int r = 0; r < 4; ++r) {
            float v = -1e30f;
#pragma unroll
            for (int j = 0; j < 8; ++j) v = fmaxf(v, acc[i][j][r]);
            v = fmaxf(v, __shfl_xor(v, 1));
            v = fmaxf(v, __shfl_xor(v, 2));
            v = fmaxf(v, __shfl_xor(v, 4));
            v = fmaxf(v, __shfl_xor(v, 8));
            if (lr == 0) sStat[wm * 32 + i * 16 + lh * 4 + r][wt] = v;
        }
    __syncthreads();   // A: also drains phase-1 loads + zero-fill stores
#pragma unroll
    for (int i = 0; i < 2; ++i)
#pragma unroll
        for (int r = 0; r < 4; ++r) {
            const int m = wm * 32 + i * 16 + lh * 4 + r;
            rmax[i][r] = fmaxf(sStat[m][0], sStat[m][1]);
        }
    __syncthreads();   // B
#pragma unroll
    for (int i = 0; i < 2; ++i)
#pragma unroll
        for (int r = 0; r < 4; ++r) {
            float s = 0.f;
#pragma unroll
            for (int j = 0; j < 8; ++j) {
                const float p = __expf(acc[i][j][r] - rmax[i][r]);
                acc[i][j][r] = p;
                s += p;
            }
            s += __shfl_xor(s, 1);
            s += __shfl_xor(s, 2);
            s += __shfl_xor(s, 4);
            s += __shfl_xor(s, 8);
            if (lr == 0) sStat[wm * 32 + i * 16 + lh * 4 + r][wt] = s;
        }
    __syncthreads();   // C
#pragma unroll
    for (int i = 0; i < 2; ++i)
#pragma unroll
        for (int r = 0; r < 4; ++r) {
            const int m = wm * 32 + i * 16 + lh * 4 + r;
            rinv[i][r] = 1.0f / (sStat[m][0] + sStat[m][1]);
        }

#pragma unroll
    for (int i = 0; i < 2; ++i)
#pragma unroll
        for (int r = 0; r < 4; ++r) {
            const int m_loc = wm * 32 + i * 16 + lh * 4 + r;
            const int ig = r0 + m_loc;
            float* orow = &outmat[(size_t)b_ * 4194304 +
                                  (size_t)(dd * 256 + ig) * 2048 + dd * 256];
#pragma unroll
            for (int j = 0; j < 8; ++j) {
                const int t = wt * 128 + j * 16 + lr;
                float a = acc[i][j][r] * rinv[i][r];
                const int d = (ig > t) ? (ig - t) : (t - ig);
                int ov = 512 - d * n; if (ov < 0) ov = 0;
                if (d == 0 || ((2 * ov >= 512) && (ov < 512))) a = 0.f;
                __builtin_nontemporal_store(a, &orow[t]);
                // sP frag-major: tchunk=t>>5, mtile=m_loc>>4
                sP[((t >> 5) * 4 + (m_loc >> 4)) * 512 +
                   (((t & 31) >> 3) * 16 + (m_loc & 15)) * 8 + (t & 7)] = f2bf(a);
            }
        }
    __syncthreads();   // D: sP ready for all waves

    // ---------------- Phase 3: out = P V (barrier-free, direct V loads) -----
    // V frag (nc, jt, tc): vb + ((bd*32 + nc*16 + wt*8 + jt)*8 + tc)*512 + lane*8
    const u16* vbase = vb + ((size_t)(bd * 32 + wt * 8) * 8) * 512 + lane * 8;

    // nc = 0
#pragma unroll
    for (int i = 0; i < 2; ++i)
#pragma unroll
        for (int j = 0; j < 8; ++j) acc[i][j] = (f32x4){0.f, 0.f, 0.f, 0.f};
#pragma unroll 2
    for (int tc = 0; tc < 8; ++tc) {
        bf16x8 af[2], bfr[8];
#pragma unroll
        for (int mt = 0; mt < 2; ++mt)
            af[mt] = *(const bf16x8*)&sP[(tc * 4 + wm * 2 + mt) * 512 + lane * 8];
#pragma unroll
        for (int jt = 0; jt < 8; ++jt)
            bfr[jt] = *(const bf16x8*)(vbase + (size_t)(jt * 8 + tc) * 512);
#pragma unroll
        for (int mt = 0; mt < 2; ++mt)
#pragma unroll
            for (int jt = 0; jt < 8; ++jt)
                acc[mt][jt] = mfma16(af[mt], bfr[jt], acc[mt][jt]);
    }
    // epilogue nc=0 (frees acc before the nc=1 loop -> lower VGPR peak)
#pragma unroll
    for (int mt = 0; mt < 2; ++mt)
#pragma unroll
        for (int jt = 0; jt < 8; ++jt) {
            const int ng = wt * 128 + jt * 16 + lr;
#pragma unroll
            for (int r = 0; r < 4; ++r) {
                const int m_loc = wm * 32 + mt * 16 + lh * 4 + r;
                __builtin_nontemporal_store(
                    acc[mt][jt][r],
                    &out[((size_t)bd * 256 + r0 + m_loc) * 512 + ng]);
            }
        }

    // nc = 1
#pragma unroll
    for (int i = 0; i < 2; ++i)
#pragma unroll
        for (int j = 0; j < 8; ++j) acc[i][j] = (f32x4){0.f, 0.f, 0.f, 0.f};
    const u16* vbase1 = vbase + (size_t)16 * 8 * 512;
#pragma unroll 2
    for (int tc = 0; tc < 8; ++tc) {
        bf16x8 af[2], bfr[8];
#pragma unroll
        for (int mt = 0; mt < 2; ++mt)
            af[mt] = *(const bf16x8*)&sP[(tc * 4 + wm * 2 + mt) * 512 + lane * 8];
#pragma unroll
        for (int jt = 0; jt < 8; ++jt)
            bfr[jt] = *(const bf16x8*)(vbase1 + (size_t)(jt * 8 + tc) * 512);
#pragma unroll
        for (int mt = 0; mt < 2; ++mt)
#pragma unroll
            for (int jt = 0; jt < 8; ++jt)
                acc[mt][jt] = mfma16(af[mt], bfr[jt], acc[mt][jt]);
    }
#pragma unroll
    for (int mt = 0; mt < 2; ++mt)
#pragma unroll
        for (int jt = 0; jt < 8; ++jt) {
            const int ng = 256 + wt * 128 + jt * 16 + lr;
#pragma unroll
            for (int r = 0; r < 4; ++r) {
                const int m_loc = wm * 32 + mt * 16 + lh * 4 + r;
                __builtin_nontemporal_store(
                    acc[mt][jt][r],
                    &out[((size_t)bd * 256 + r0 + m_loc) * 512 + ng]);
            }
        }
}

// ---------------------------------------------------------------------------
extern "C" void kernel_launch(void* const* d_in, const int* in_sizes, int n_in,
                              void* d_out, int out_size, void* d_ws, size_t ws_size,
                              hipStream_t stream) {
    (void)in_sizes; (void)n_in; (void)out_size; (void)ws_size;
    const float* x     = (const float*)d_in[0];
    const float* Wqkv  = (const float*)d_in[1];
    const float* bqkv  = (const float*)d_in[2];
    const int*   n_ptr = (const int*)d_in[3];

    float* out    = (float*)d_out;
    float* outmat = out + (size_t)16 * 2048 * 512;

    u16* xb = (u16*)d_ws;                 // 16,777,216
    u16* wb = xb + 16777216;              //    786,432
    u16* qb = wb + 786432;                // 16,777,216
    u16* kb = qb + 16777216;              // 16,777,216
    u16* vb = kb + 16777216;              // 16,777,216

    cast_bf16<<<8576, 256, 0, stream>>>(x, Wqkv, xb, wb);

    qkv_gemm<<<1536, 256, 0, stream>>>(xb, wb, bqkv, qb, kb, vb);

    attn_kernel<<<512, 256, 0, stream>>>(qb, kb, vb, n_ptr, out, outmat);
}

// Round 3
// 516.253 us; speedup vs baseline: 1.0518x; 1.0518x over previous
//
#include <hip/hip_runtime.h>
#include <hip/hip_bf16.h>
#include <cstdint>

// B=16, D=8, S=256, L=512, BD=128, M=32768, F=1536
// d_out = [output: 16*2048*512] ++ [output_matrix_attn: 16*2048*2048], fp32.
//
// Fragment-major layouts (16x16x32 bf16 MFMA, lane l, elem j):
//   A-type frag: X[m = tile*16 + (l&15)][k = kchunk*32 + (l>>4)*8 + j]
//   qb[bd][mtile16][kchunk16][512], kb[bd][ttile16][kchunk16][512],
//   vb[bd][ntile32][tchunk8][512]  (V stored transposed: lane&15 = n, elems = t)

typedef unsigned short u16;
typedef short bf16x8 __attribute__((ext_vector_type(8)));
typedef float f32x4 __attribute__((ext_vector_type(4)));

__device__ __forceinline__ u16 f2bf(float f) {
    union { float f; unsigned int u; } v; v.f = f;
    unsigned int r = v.u + 0x7FFF + ((v.u >> 16) & 1);
    return (u16)(r >> 16);
}

__device__ __forceinline__ void gload16(const u16* g, u16* l) {
    __builtin_amdgcn_global_load_lds(
        (const __attribute__((address_space(1))) unsigned int*)g,
        (__attribute__((address_space(3))) unsigned int*)l, 16, 0, 0);
}

__device__ __forceinline__ f32x4 mfma16(bf16x8 a, bf16x8 b, f32x4 c) {
    return __builtin_amdgcn_mfma_f32_16x16x32_bf16(a, b, c, 0, 0, 0);
}

// ---------------------------------------------------------------------------
// Kernel 0: fp32 -> bf16 cast of x and Wqkv.
// ---------------------------------------------------------------------------
__global__ __launch_bounds__(256) void cast_bf16(const float* __restrict__ x,
                                                 const float* __restrict__ w,
                                                 u16* __restrict__ xb,
                                                 u16* __restrict__ wb) {
    const size_t NX = 16777216 / 8, NW = 786432 / 8;
    size_t i = (size_t)blockIdx.x * 256 + threadIdx.x;
    const float* src; u16* dst; size_t e;
    if (i < NX)            { src = x; dst = xb; e = i; }
    else if (i < NX + NW)  { src = w; dst = wb; e = i - NX; }
    else return;
    const float4 a = *(const float4*)&src[e * 8];
    const float4 b = *(const float4*)&src[e * 8 + 4];
    u16 o[8] = { f2bf(a.x), f2bf(a.y), f2bf(a.z), f2bf(a.w),
                 f2bf(b.x), f2bf(b.y), f2bf(b.z), f2bf(b.w) };
    *(uint4*)&dst[e * 8] = *(const uint4*)o;
}

// ---------------------------------------------------------------------------
// Kernel 1: QKV projection, bf16 MFMA, fragment-major epilogue.
// Block 128m x 256f, BK=32, 4 waves, wave = 64m x 128f.
// T3-minimum pipeline: dbuf LDS, STAGE(next) issued BEFORE compute(cur),
// one vmcnt(0)+s_barrier per k-step AFTER the MFMAs (load latency hides
// under the 32-MFMA compute phase instead of being drained cold).
// ---------------------------------------------------------------------------
__global__ __launch_bounds__(256, 2) void qkv_gemm(const u16* __restrict__ xb,
                                                   const u16* __restrict__ wb,
                                                   const float* __restrict__ bias,
                                                   u16* __restrict__ qb,
                                                   u16* __restrict__ kb,
                                                   u16* __restrict__ vb) {
    __shared__ __align__(16) u16 sA[2][8 * 512];    // 16 KB (dbuf A; buf0 = epi patch)
    __shared__ __align__(16) u16 sB[2][16 * 512];   // 32 KB (dbuf B)
    const int tid = threadIdx.x, lane = tid & 63, w = tid >> 6;
    const int lr = lane & 15, lh = lane >> 4;
    const int bfl = blockIdx.x;
    const int work = (bfl & 7) * 192 + (bfl >> 3);   // bijective XCD swizzle
    const int mb = work / 6;
    const int fb = work - mb * 6;
    const int f0 = fb * 256, m0 = mb * 128;
    const int wm = w & 1, wf = w >> 1;

    f32x4 acc[4][8];
#pragma unroll
    for (int i = 0; i < 4; ++i)
#pragma unroll
        for (int j = 0; j < 8; ++j) acc[i][j] = (f32x4){0.f, 0.f, 0.f, 0.f};

    // Prologue: stage k-step 0 into buffer 0, cold drain.
#pragma unroll
    for (int i = 0; i < 6; ++i) {
        const int j = w * 6 + i;
        if (j < 8)
            gload16(xb + (size_t)(m0 + j * 16 + lr) * 512 + 0 + lh * 8,
                    &sA[0][j * 512]);
        else
            gload16(wb + (size_t)(f0 + (j - 8) * 16 + lr) * 512 + 0 + lh * 8,
                    &sB[0][(j - 8) * 512]);
    }
    asm volatile("s_waitcnt vmcnt(0)" ::: "memory");
    __builtin_amdgcn_s_barrier();
    __builtin_amdgcn_sched_barrier(0);

#pragma unroll 1
    for (int kc = 0; kc < 16; ++kc) {
        const int cur = kc & 1;
        if (kc < 15) {                               // stage NEXT k-step first
            const int k0 = (kc + 1) * 32;
#pragma unroll
            for (int i = 0; i < 6; ++i) {
                const int j = w * 6 + i;
                if (j < 8)
                    gload16(xb + (size_t)(m0 + j * 16 + lr) * 512 + k0 + lh * 8,
                            &sA[cur ^ 1][j * 512]);
                else
                    gload16(wb + (size_t)(f0 + (j - 8) * 16 + lr) * 512 + k0 + lh * 8,
                            &sB[cur ^ 1][(j - 8) * 512]);
            }
        }
        bf16x8 af[4], bf[8];
#pragma unroll
        for (int mt = 0; mt < 4; ++mt)
            af[mt] = *(const bf16x8*)&sA[cur][(wm * 4 + mt) * 512 + lane * 8];
#pragma unroll
        for (int ft = 0; ft < 8; ++ft)
            bf[ft] = *(const bf16x8*)&sB[cur][(wf * 8 + ft) * 512 + lane * 8];
#pragma unroll
        for (int mt = 0; mt < 4; ++mt)
#pragma unroll
            for (int ft = 0; ft < 8; ++ft)
                acc[mt][ft] = mfma16(af[mt], bf[ft], acc[mt][ft]);
        if (kc < 15) {
            // next-buffer loads had the whole MFMA phase to land; ds_reads of
            // cur are retired (MFMAs consumed them) so next stage can't race.
            asm volatile("s_waitcnt vmcnt(0)" ::: "memory");
            __builtin_amdgcn_s_barrier();
            __builtin_amdgcn_sched_barrier(0);
        }
    }
    __syncthreads();   // close last k-step's LDS reads before patch reuse

    // ---- Epilogue: LDS bounce C-layout -> fragment-major, 16B stores ----
    u16* patch = &sA[0][w * 1024];   // 2 KB per wave; patch row stride 40 u16
    const int bdq = m0 >> 8;
    float bv[8];
#pragma unroll
    for (int ft = 0; ft < 8; ++ft) bv[ft] = bias[f0 + wf * 128 + ft * 16 + lr];

    if (f0 < 1024) {
        u16* dstb = (f0 < 512) ? qb : kb;
        const int mtileg = ((m0 & 255) >> 4) + wm * 4;
        const int kbase = ((f0 & 511) + wf * 128) >> 5;
#pragma unroll
        for (int mt = 0; mt < 4; ++mt)
#pragma unroll
            for (int ftp = 0; ftp < 4; ++ftp) {
#pragma unroll
                for (int h = 0; h < 2; ++h) {
                    const int ft = ftp * 2 + h;
                    const f32x4 a = acc[mt][ft];
#pragma unroll
                    for (int r = 0; r < 4; ++r)
                        patch[(lh * 4 + r) * 40 + h * 16 + lr] = f2bf(a[r] + bv[ft]);
                }
                asm volatile("s_waitcnt lgkmcnt(0)" ::: "memory");
                bf16x8 frag = *(const bf16x8*)&patch[lr * 40 + lh * 8];
                u16* dst = dstb +
                    ((size_t)(bdq * 16 + mtileg + mt) * 16 + (kbase + ftp)) * 512 +
                    lane * 8;
                *(bf16x8*)dst = frag;
            }
    } else {
        const int nbase = ((f0 - 1024) >> 4) + wf * 8;
        const int tbase = ((m0 & 255) >> 5) + wm * 2;
#pragma unroll
        for (int ft = 0; ft < 8; ++ft)
#pragma unroll
            for (int mtp = 0; mtp < 2; ++mtp) {
#pragma unroll
                for (int h = 0; h < 2; ++h) {
                    const f32x4 a = acc[mtp * 2 + h][ft];
#pragma unroll
                    for (int r = 0; r < 4; ++r)
                        patch[lr * 40 + h * 16 + lh * 4 + r] = f2bf(a[r] + bv[ft]);
                }
                asm volatile("s_waitcnt lgkmcnt(0)" ::: "memory");
                bf16x8 frag = *(const bf16x8*)&patch[lr * 40 + lh * 8];
                u16* dst = vb +
                    ((size_t)(bdq * 32 + nbase + ft) * 8 + (tbase + mtp)) * 512 +
                    lane * 8;
                *(bf16x8*)dst = frag;
            }
    }
}

// ---------------------------------------------------------------------------
// Kernel 2: attention (round-1 version, best measured). Flat grid 512
// (64 q-rows x bd), XCD-swizzled. Phase 1: dbuf Q/K + counted vmcnt(8)
// (zero-fill stores stay in flight) + one raw barrier per k-step.
// Phase 3: dbuf V, stage-early + vmcnt(0), V prefetched during softmax.
// ---------------------------------------------------------------------------
__global__ __launch_bounds__(256, 2) void attn_kernel(const u16* __restrict__ qb,
                                                      const u16* __restrict__ kb,
                                                      const u16* __restrict__ vb,
                                                      const int* __restrict__ n_ptr,
                                                      float* __restrict__ out,
                                                      float* __restrict__ outmat) {
    __shared__ __align__(16) u16 sQ[2][4 * 512];    // 8 KB  (dbuf Q)
    __shared__ __align__(16) u16 sK[2][16 * 512];   // 32 KB (dbuf K, then dbuf V)
    __shared__ __align__(16) u16 sP[8 * 4 * 512];   // 32 KB frag-major P
    __shared__ float sStat[64][2];

    const int tid = threadIdx.x, lane = tid & 63, w = tid >> 6;
    const int lr = lane & 15, lh = lane >> 4;
    const int bfl = blockIdx.x;
    const int work = (bfl & 7) * 64 + (bfl >> 3);
    const int bd = work >> 2, rblk = work & 3;
    const int r0 = rblk * 64;
    const int n = *n_ptr;
    const int wm = w & 1, wt = w >> 1;
    const int b_ = bd >> 3, dd = bd & 7;
    float* zbase = &outmat[(size_t)b_ * 4194304 + (size_t)(dd * 256 + r0) * 2048];
    const float4 f4z = make_float4(0.f, 0.f, 0.f, 0.f);

    f32x4 acc[2][8];
#pragma unroll
    for (int i = 0; i < 2; ++i)
#pragma unroll
        for (int j = 0; j < 8; ++j) acc[i][j] = (f32x4){0.f, 0.f, 0.f, 0.f};

    // ---------------- Phase 1: scores = Q K^T ----------------
    {
#pragma unroll
        for (int i = 0; i < 5; ++i) {
            const int j = w * 5 + i;
            if (j < 4)
                gload16(qb + ((size_t)(bd * 16 + rblk * 4 + j) * 16 + 0) * 512 +
                        lane * 8, &sQ[0][j * 512]);
            else
                gload16(kb + ((size_t)(bd * 16 + (j - 4)) * 16 + 0) * 512 + lane * 8,
                        &sK[0][(j - 4) * 512]);
        }
        __builtin_amdgcn_sched_barrier(0);   // pin: loads issue before stores
#pragma unroll
        for (int u = 0; u < 8; ++u) {
            const int idx = u * 256 + tid;
            *(float4*)&zbase[(size_t)(idx >> 9) * 2048 + (idx & 511) * 4] = f4z;
        }
        asm volatile("s_waitcnt vmcnt(8)" ::: "memory");  // loads done, stores fly
        __builtin_amdgcn_s_barrier();
        __builtin_amdgcn_sched_barrier(0);
    }

#pragma unroll 1
    for (int kc = 0; kc < 16; ++kc) {
        const int cur = kc & 1;
        if (kc < 15) {
#pragma unroll
            for (int i = 0; i < 5; ++i) {
                const int j = w * 5 + i;
                if (j < 4)
                    gload16(qb + ((size_t)(bd * 16 + rblk * 4 + j) * 16 + (kc + 1)) * 512 +
                            lane * 8, &sQ[cur ^ 1][j * 512]);
                else
                    gload16(kb + ((size_t)(bd * 16 + (j - 4)) * 16 + (kc + 1)) * 512 +
                            lane * 8, &sK[cur ^ 1][(j - 4) * 512]);
            }
            __builtin_amdgcn_sched_barrier(0);   // pin: loads before zero-fill
#pragma unroll
            for (int u = 0; u < 8; ++u) {
                const int idx = ((kc + 1) * 8 + u) * 256 + tid;
                *(float4*)&zbase[(size_t)(idx >> 9) * 2048 + (idx & 511) * 4] = f4z;
            }
        }
        bf16x8 af[2], bfr[8];
#pragma unroll
        for (int mt = 0; mt < 2; ++mt)
            af[mt] = *(const bf16x8*)&sQ[cur][(wm * 2 + mt) * 512 + lane * 8];
#pragma unroll
        for (int jt = 0; jt < 8; ++jt)
            bfr[jt] = *(const bf16x8*)&sK[cur][(wt * 8 + jt) * 512 + lane * 8];
#pragma unroll
        for (int mt = 0; mt < 2; ++mt)
#pragma unroll
            for (int jt = 0; jt < 8; ++jt)
                acc[mt][jt] = mfma16(af[mt], bfr[jt], acc[mt][jt]);
        if (kc < 15) {
            asm volatile("s_waitcnt vmcnt(8)" ::: "memory");
            __builtin_amdgcn_s_barrier();
            __builtin_amdgcn_sched_barrier(0);
        }
    }

    // ---------------- Phase 2: softmax + mask ----------------
    const float scale = 0.044194173824159216f;
#pragma unroll
    for (int i = 0; i < 2; ++i)
#pragma unroll
        for (int j = 0; j < 8; ++j) acc[i][j] *= scale;

    float rmax[2][4], rinv[2][4];
#pragma unroll
    for (int i = 0; i < 2; ++i)
#pragma unroll
        for (int r = 0; r < 4; ++r) {
            float v = -1e30f;
#pragma unroll
            for (int j = 0; j < 8; ++j) v = fmaxf(v, acc[i][j][r]);
            v = fmaxf(v, __shfl_xor(v, 1));
            v = fmaxf(v, __shfl_xor(v, 2));
            v = fmaxf(v, __shfl_xor(v, 4));
            v = fmaxf(v, __shfl_xor(v, 8));
            if (lr == 0) sStat[wm * 32 + i * 16 + lh * 4 + r][wt] = v;
        }
    __syncthreads();   // A
#pragma unroll
    for (int i = 0; i < 2; ++i)
#pragma unroll
        for (int r = 0; r < 4; ++r) {
            const int m = wm * 32 + i * 16 + lh * 4 + r;
            rmax[i][r] = fmaxf(sStat[m][0], sStat[m][1]);
        }
    __syncthreads();   // B
#pragma unroll
    for (int i = 0; i < 2; ++i)
#pragma unroll
        for (int r = 0; r < 4; ++r) {
            float s = 0.f;
#pragma unroll
            for (int j = 0; j < 8; ++j) {
                const float p = __expf(acc[i][j][r] - rmax[i][r]);
                acc[i][j][r] = p;
                s += p;
            }
            s += __shfl_xor(s, 1);
            s += __shfl_xor(s, 2);
            s += __shfl_xor(s, 4);
            s += __shfl_xor(s, 8);
            if (lr == 0) sStat[wm * 32 + i * 16 + lh * 4 + r][wt] = s;
        }
    __syncthreads();   // C

    // T14: prefetch phase-3 step-0 V tiles into sK[0] now; sync D drains them.
#pragma unroll
    for (int i = 0; i < 4; ++i) {
        const int nt = w * 4 + i;
        gload16(vb + ((size_t)(bd * 32 + nt) * 8 + 0) * 512 + lane * 8,
                &sK[0][nt * 512]);
    }

#pragma unroll
    for (int i = 0; i < 2; ++i)
#pragma unroll
        for (int r = 0; r < 4; ++r) {
            const int m = wm * 32 + i * 16 + lh * 4 + r;
            rinv[i][r] = 1.0f / (sStat[m][0] + sStat[m][1]);
        }

#pragma unroll
    for (int i = 0; i < 2; ++i)
#pragma unroll
        for (int r = 0; r < 4; ++r) {
            const int m_loc = wm * 32 + i * 16 + lh * 4 + r;
            const int ig = r0 + m_loc;
            float* orow = &outmat[(size_t)b_ * 4194304 +
                                  (size_t)(dd * 256 + ig) * 2048 + dd * 256];
#pragma unroll
            for (int j = 0; j < 8; ++j) {
                const int t = wt * 128 + j * 16 + lr;
                float a = acc[i][j][r] * rinv[i][r];
                const int d = (ig > t) ? (ig - t) : (t - ig);
                int ov = 512 - d * n; if (ov < 0) ov = 0;
                if (d == 0 || ((2 * ov >= 512) && (ov < 512))) a = 0.f;
                orow[t] = a;
                sP[((t >> 5) * 4 + (m_loc >> 4)) * 512 +
                   (((t & 31) >> 3) * 16 + (m_loc & 15)) * 8 + (t & 7)] = f2bf(a);
            }
        }
    __syncthreads();   // D: drains V prefetch (vmcnt) + sP writes (lgkm)

    // ---------------- Phase 3: out = P V (dbuf V, stage-early) ----------------
    f32x4 accB[2][8];
#pragma unroll
    for (int i = 0; i < 2; ++i)
#pragma unroll
        for (int j = 0; j < 8; ++j) acc[i][j] = (f32x4){0.f, 0.f, 0.f, 0.f};

#pragma unroll 1
    for (int step = 0; step < 8; ++step) {
        const int cur = step & 1;
        const int ns = step + 1;
#pragma unroll
        for (int i = 0; i < 4; ++i) {
            const int nt = w * 4 + i;
            gload16(vb + ((size_t)(bd * 32 + (ns >> 3) * 16 + nt) * 8 + (ns & 7)) * 512 +
                    lane * 8, &sK[cur ^ 1][nt * 512]);
        }
        bf16x8 af[2], bfr[8];
#pragma unroll
        for (int mt = 0; mt < 2; ++mt)
            af[mt] = *(const bf16x8*)&sP[(step * 4 + wm * 2 + mt) * 512 + lane * 8];
#pragma unroll
        for (int jt = 0; jt < 8; ++jt)
            bfr[jt] = *(const bf16x8*)&sK[cur][(wt * 8 + jt) * 512 + lane * 8];
#pragma unroll
        for (int mt = 0; mt < 2; ++mt)
#pragma unroll
            for (int jt = 0; jt < 8; ++jt)
                acc[mt][jt] = mfma16(af[mt], bfr[jt], acc[mt][jt]);
        asm volatile("s_waitcnt vmcnt(0)" ::: "memory");
        __builtin_amdgcn_s_barrier();
        __builtin_amdgcn_sched_barrier(0);
    }

#pragma unroll
    for (int i = 0; i < 2; ++i)
#pragma unroll
        for (int j = 0; j < 8; ++j) accB[i][j] = (f32x4){0.f, 0.f, 0.f, 0.f};

#pragma unroll 1
    for (int step = 8; step < 16; ++step) {
        const int cur = step & 1, tc = step & 7;
        if (step < 15) {
            const int ns = step + 1;
#pragma unroll
            for (int i = 0; i < 4; ++i) {
                const int nt = w * 4 + i;
                gload16(vb + ((size_t)(bd * 32 + 16 + nt) * 8 + (ns & 7)) * 512 +
                        lane * 8, &sK[cur ^ 1][nt * 512]);
            }
        }
        bf16x8 af[2], bfr[8];
#pragma unroll
        for (int mt = 0; mt < 2; ++mt)
            af[mt] = *(const bf16x8*)&sP[(tc * 4 + wm * 2 + mt) * 512 + lane * 8];
#pragma unroll
        for (int jt = 0; jt < 8; ++jt)
            bfr[jt] = *(const bf16x8*)&sK[cur][(wt * 8 + jt) * 512 + lane * 8];
#pragma unroll
        for (int mt = 0; mt < 2; ++mt)
#pragma unroll
            for (int jt = 0; jt < 8; ++jt)
                accB[mt][jt] = mfma16(af[mt], bfr[jt], accB[mt][jt]);
        if (step < 15) {
            asm volatile("s_waitcnt vmcnt(0)" ::: "memory");
            __builtin_amdgcn_s_barrier();
            __builtin_amdgcn_sched_barrier(0);
        }
    }

    // Fused epilogue: both nc halves.
#pragma unroll
    for (int mt = 0; mt < 2; ++mt)
#pragma unroll
        for (int jt = 0; jt < 8; ++jt) {
            const int ng = wt * 128 + jt * 16 + lr;
#pragma unroll
            for (int r = 0; r < 4; ++r) {
                const int m_loc = wm * 32 + mt * 16 + lh * 4 + r;
                float* orow = &out[((size_t)bd * 256 + r0 + m_loc) * 512];
                orow[ng] = acc[mt][jt][r];
                orow[256 + ng] = accB[mt][jt][r];
            }
        }
}

// ---------------------------------------------------------------------------
extern "C" void kernel_launch(void* const* d_in, const int* in_sizes, int n_in,
                              void* d_out, int out_size, void* d_ws, size_t ws_size,
                              hipStream_t stream) {
    (void)in_sizes; (void)n_in; (void)out_size; (void)ws_size;
    const float* x     = (const float*)d_in[0];
    const float* Wqkv  = (const float*)d_in[1];
    const float* bqkv  = (const float*)d_in[2];
    const int*   n_ptr = (const int*)d_in[3];

    float* out    = (float*)d_out;
    float* outmat = out + (size_t)16 * 2048 * 512;

    u16* xb = (u16*)d_ws;                 // 16,777,216
    u16* wb = xb + 16777216;              //    786,432
    u16* qb = wb + 786432;                // 16,777,216
    u16* kb = qb + 16777216;              // 16,777,216
    u16* vb = kb + 16777216;              // 16,777,216

    cast_bf16<<<8576, 256, 0, stream>>>(x, Wqkv, xb, wb);

    qkv_gemm<<<1536, 256, 0, stream>>>(xb, wb, bqkv, qb, kb, vb);

    attn_kernel<<<512, 256, 0, stream>>>(qb, kb, vb, n_ptr, out, outmat);
}

// Round 5
// 470.439 us; speedup vs baseline: 1.1542x; 1.0974x over previous
//
#include <hip/hip_runtime.h>
#include <hip/hip_bf16.h>
#include <cstdint>

// B=16, D=8, S=256, L=512, BD=128, M=32768, F=1536
// d_out = [output: 16*2048*512] ++ [output_matrix_attn: 16*2048*2048], fp32.
//
// Fragment-major layouts (16x16x32 bf16 MFMA, lane l, elem j):
//   A-type frag: X[m = tile*16 + (l&15)][k = kchunk*32 + (l>>4)*8 + j]
//   qb[bd][mtile16][kchunk16][512], kb[bd][ttile16][kchunk16][512],
//   vb[bd][ntile32][tchunk8][512]  (V stored transposed: lane&15 = n, elems = t)
//
// R5 (= R4 + race fix): outmat zero-fill relocated from attn's phase-1
// critical path into qkv's k-loop. Race fix: EXACTLY 3 fill stores per
// k-step (overflow chunks wrap to the start, rewriting zeros -- benign
// identical-value stores) so the FIFO invariant behind vmcnt(3) holds:
// at the wait, in-flight = [<=3 old stores][6 loads][3 new stores];
// vmcnt(3) provably retires all 6 staged loads every iteration.

typedef unsigned short u16;
typedef short bf16x8 __attribute__((ext_vector_type(8)));
typedef float f32x4 __attribute__((ext_vector_type(4)));

__device__ __forceinline__ u16 f2bf(float f) {
    union { float f; unsigned int u; } v; v.f = f;
    unsigned int r = v.u + 0x7FFF + ((v.u >> 16) & 1);
    return (u16)(r >> 16);
}

__device__ __forceinline__ void gload16(const u16* g, u16* l) {
    __builtin_amdgcn_global_load_lds(
        (const __attribute__((address_space(1))) unsigned int*)g,
        (__attribute__((address_space(3))) unsigned int*)l, 16, 0, 0);
}

__device__ __forceinline__ f32x4 mfma16(bf16x8 a, bf16x8 b, f32x4 c) {
    return __builtin_amdgcn_mfma_f32_16x16x32_bf16(a, b, c, 0, 0, 0);
}

// ---------------------------------------------------------------------------
// Kernel 0: fp32 -> bf16 cast of x and Wqkv.
// ---------------------------------------------------------------------------
__global__ __launch_bounds__(256) void cast_bf16(const float* __restrict__ x,
                                                 const float* __restrict__ w,
                                                 u16* __restrict__ xb,
                                                 u16* __restrict__ wb) {
    const size_t NX = 16777216 / 8, NW = 786432 / 8;
    size_t i = (size_t)blockIdx.x * 256 + threadIdx.x;
    const float* src; u16* dst; size_t e;
    if (i < NX)            { src = x; dst = xb; e = i; }
    else if (i < NX + NW)  { src = w; dst = wb; e = i - NX; }
    else return;
    const float4 a = *(const float4*)&src[e * 8];
    const float4 b = *(const float4*)&src[e * 8 + 4];
    u16 o[8] = { f2bf(a.x), f2bf(a.y), f2bf(a.z), f2bf(a.w),
                 f2bf(b.x), f2bf(b.y), f2bf(b.z), f2bf(b.w) };
    *(uint4*)&dst[e * 8] = *(const uint4*)o;
}

// ---------------------------------------------------------------------------
// Kernel 1: QKV projection + outmat zero-fill rider.
// Block 128m x 256f, BK=32, 4 waves, wave = 64m x 128f, dbuf LDS.
// Zero-fill: chunk c = (kc*3+u)*1536 + bfl; overflow (c >= 57344) wraps to
// c - 57344 (duplicate zero write, benign). Each chunk = 256 contiguous
// float4 (tid-indexed) over the 14,680,064 zero slots of outmat.
// ---------------------------------------------------------------------------
__global__ __launch_bounds__(256, 2) void qkv_gemm(const u16* __restrict__ xb,
                                                   const u16* __restrict__ wb,
                                                   const float* __restrict__ bias,
                                                   u16* __restrict__ qb,
                                                   u16* __restrict__ kb,
                                                   u16* __restrict__ vb,
                                                   float* __restrict__ outmat) {
    __shared__ __align__(16) u16 sA[2][8 * 512];    // 16 KB (dbuf A; buf0 = epi patch)
    __shared__ __align__(16) u16 sB[2][16 * 512];   // 32 KB (dbuf B)
    const int tid = threadIdx.x, lane = tid & 63, w = tid >> 6;
    const int lr = lane & 15, lh = lane >> 4;
    const int bfl = blockIdx.x;
    const int work = (bfl & 7) * 192 + (bfl >> 3);   // bijective XCD swizzle
    const int mb = work / 6;
    const int fb = work - mb * 6;
    const int f0 = fb * 256, m0 = mb * 128;
    const int wm = w & 1, wf = w >> 1;

    f32x4 acc[4][8];
#pragma unroll
    for (int i = 0; i < 4; ++i)
#pragma unroll
        for (int j = 0; j < 8; ++j) acc[i][j] = (f32x4){0.f, 0.f, 0.f, 0.f};

    // Prologue: stage k-step 0 into buffer 0, cold drain (no stores yet).
#pragma unroll
    for (int i = 0; i < 6; ++i) {
        const int j = w * 6 + i;
        if (j < 8)
            gload16(xb + (size_t)(m0 + j * 16 + lr) * 512 + 0 + lh * 8,
                    &sA[0][j * 512]);
        else
            gload16(wb + (size_t)(f0 + (j - 8) * 16 + lr) * 512 + 0 + lh * 8,
                    &sB[0][(j - 8) * 512]);
    }
    asm volatile("s_waitcnt vmcnt(0)" ::: "memory");
    __builtin_amdgcn_s_barrier();
    __builtin_amdgcn_sched_barrier(0);

#pragma unroll 1
    for (int kc = 0; kc < 16; ++kc) {
        const int cur = kc & 1;
        if (kc < 15) {                               // stage NEXT k-step first
            const int k0 = (kc + 1) * 32;
#pragma unroll
            for (int i = 0; i < 6; ++i) {
                const int j = w * 6 + i;
                if (j < 8)
                    gload16(xb + (size_t)(m0 + j * 16 + lr) * 512 + k0 + lh * 8,
                            &sA[cur ^ 1][j * 512]);
                else
                    gload16(wb + (size_t)(f0 + (j - 8) * 16 + lr) * 512 + k0 + lh * 8,
                            &sB[cur ^ 1][(j - 8) * 512]);
            }
        }
        __builtin_amdgcn_sched_barrier(0);   // pin: loads issue before fill stores
        // ---- zero-fill rider: EXACTLY 3 NT float4 stores/thread/step ----
#pragma unroll
        for (int u = 0; u < 3; ++u) {
            const unsigned c0 = (unsigned)(kc * 3 + u) * 1536u + (unsigned)bfl;
            const unsigned c = (c0 < 57344u) ? c0 : (c0 - 57344u);  // wrap: dup zero
            const unsigned z = c * 256u + (unsigned)tid;
            const unsigned rg = (z >> 6) / 7u;       // z / 448 (448 zero-f4 per row)
            const unsigned c448 = z - rg * 448u;
            const unsigned b = rg >> 11, rowin = rg & 2047u;
            const unsigned ddr = rowin >> 8;
            const unsigned col4 = c448 + (c448 >= ddr * 64u ? 64u : 0u);
            const f32x4 zz = (f32x4){0.f, 0.f, 0.f, 0.f};
            __builtin_nontemporal_store(
                zz, (f32x4*)&outmat[(((size_t)b << 20) + rowin * 512u + col4) * 4]);
        }
        bf16x8 af[4], bf[8];
#pragma unroll
        for (int mt = 0; mt < 4; ++mt)
            af[mt] = *(const bf16x8*)&sA[cur][(wm * 4 + mt) * 512 + lane * 8];
#pragma unroll
        for (int ft = 0; ft < 8; ++ft)
            bf[ft] = *(const bf16x8*)&sB[cur][(wf * 8 + ft) * 512 + lane * 8];
#pragma unroll
        for (int mt = 0; mt < 4; ++mt)
#pragma unroll
            for (int ft = 0; ft < 8; ++ft)
                acc[mt][ft] = mfma16(af[mt], bf[ft], acc[mt][ft]);
        if (kc < 15) {
            // FIFO vmcnt: [<=3 old stores][6 loads][3 new stores] in flight;
            // vmcnt(3) retires everything except this step's 3 stores ->
            // staged loads provably done, fill stores never stall the barrier.
            asm volatile("s_waitcnt vmcnt(3)" ::: "memory");
            __builtin_amdgcn_s_barrier();
            __builtin_amdgcn_sched_barrier(0);
        }
    }
    __syncthreads();   // close last k-step's LDS reads + drain all stores

    // ---- Epilogue: LDS bounce C-layout -> fragment-major, 16B stores ----
    u16* patch = &sA[0][w * 1024];   // 2 KB per wave; patch row stride 40 u16
    const int bdq = m0 >> 8;
    float bv[8];
#pragma unroll
    for (int ft = 0; ft < 8; ++ft) bv[ft] = bias[f0 + wf * 128 + ft * 16 + lr];

    if (f0 < 1024) {
        u16* dstb = (f0 < 512) ? qb : kb;
        const int mtileg = ((m0 & 255) >> 4) + wm * 4;
        const int kbase = ((f0 & 511) + wf * 128) >> 5;
#pragma unroll
        for (int mt = 0; mt < 4; ++mt)
#pragma unroll
            for (int ftp = 0; ftp < 4; ++ftp) {
#pragma unroll
                for (int h = 0; h < 2; ++h) {
                    const int ft = ftp * 2 + h;
                    const f32x4 a = acc[mt][ft];
#pragma unroll
                    for (int r = 0; r < 4; ++r)
                        patch[(lh * 4 + r) * 40 + h * 16 + lr] = f2bf(a[r] + bv[ft]);
                }
                asm volatile("s_waitcnt lgkmcnt(0)" ::: "memory");
                bf16x8 frag = *(const bf16x8*)&patch[lr * 40 + lh * 8];
                u16* dst = dstb +
                    ((size_t)(bdq * 16 + mtileg + mt) * 16 + (kbase + ftp)) * 512 +
                    lane * 8;
                *(bf16x8*)dst = frag;
            }
    } else {
        const int nbase = ((f0 - 1024) >> 4) + wf * 8;
        const int tbase = ((m0 & 255) >> 5) + wm * 2;
#pragma unroll
        for (int ft = 0; ft < 8; ++ft)
#pragma unroll
            for (int mtp = 0; mtp < 2; ++mtp) {
#pragma unroll
                for (int h = 0; h < 2; ++h) {
                    const f32x4 a = acc[mtp * 2 + h][ft];
#pragma unroll
                    for (int r = 0; r < 4; ++r)
                        patch[lr * 40 + h * 16 + lh * 4 + r] = f2bf(a[r] + bv[ft]);
                }
                asm volatile("s_waitcnt lgkmcnt(0)" ::: "memory");
                bf16x8 frag = *(const bf16x8*)&patch[lr * 40 + lh * 8];
                u16* dst = vb +
                    ((size_t)(bdq * 32 + nbase + ft) * 8 + (tbase + mtp)) * 512 +
                    lane * 8;
                *(bf16x8*)dst = frag;
            }
    }
}

// ---------------------------------------------------------------------------
// Kernel 2: attention. Flat grid 512 (64 q-rows x bd), XCD-swizzled.
// Phase 1: clean load-only dbuf (zero-fill moved to qkv) -> vmcnt(0) waits
// never touch stores. Phase 3: dbuf V, stage-early, V prefetched in softmax.
// ---------------------------------------------------------------------------
__global__ __launch_bounds__(256, 2) void attn_kernel(const u16* __restrict__ qb,
                                                      const u16* __restrict__ kb,
                                                      const u16* __restrict__ vb,
                                                      const int* __restrict__ n_ptr,
                                                      float* __restrict__ out,
                                                      float* __restrict__ outmat) {
    __shared__ __align__(16) u16 sQ[2][4 * 512];    // 8 KB  (dbuf Q)
    __shared__ __align__(16) u16 sK[2][16 * 512];   // 32 KB (dbuf K, then dbuf V)
    __shared__ __align__(16) u16 sP[8 * 4 * 512];   // 32 KB frag-major P
    __shared__ float sStat[64][2];

    const int tid = threadIdx.x, lane = tid & 63, w = tid >> 6;
    const int lr = lane & 15, lh = lane >> 4;
    const int bfl = blockIdx.x;
    const int work = (bfl & 7) * 64 + (bfl >> 3);
    const int bd = work >> 2, rblk = work & 3;
    const int r0 = rblk * 64;
    const int n = *n_ptr;
    const int wm = w & 1, wt = w >> 1;
    const int b_ = bd >> 3, dd = bd & 7;

    f32x4 acc[2][8];
#pragma unroll
    for (int i = 0; i < 2; ++i)
#pragma unroll
        for (int j = 0; j < 8; ++j) acc[i][j] = (f32x4){0.f, 0.f, 0.f, 0.f};

    // ---------------- Phase 1: scores = Q K^T (dbuf, load-only) -------------
    {
#pragma unroll
        for (int i = 0; i < 5; ++i) {
            const int j = w * 5 + i;
            if (j < 4)
                gload16(qb + ((size_t)(bd * 16 + rblk * 4 + j) * 16 + 0) * 512 +
                        lane * 8, &sQ[0][j * 512]);
            else
                gload16(kb + ((size_t)(bd * 16 + (j - 4)) * 16 + 0) * 512 + lane * 8,
                        &sK[0][(j - 4) * 512]);
        }
        asm volatile("s_waitcnt vmcnt(0)" ::: "memory");
        __builtin_amdgcn_s_barrier();
        __builtin_amdgcn_sched_barrier(0);
    }

#pragma unroll 1
    for (int kc = 0; kc < 16; ++kc) {
        const int cur = kc & 1;
        if (kc < 15) {
#pragma unroll
            for (int i = 0; i < 5; ++i) {
                const int j = w * 5 + i;
                if (j < 4)
                    gload16(qb + ((size_t)(bd * 16 + rblk * 4 + j) * 16 + (kc + 1)) * 512 +
                            lane * 8, &sQ[cur ^ 1][j * 512]);
                else
                    gload16(kb + ((size_t)(bd * 16 + (j - 4)) * 16 + (kc + 1)) * 512 +
                            lane * 8, &sK[cur ^ 1][(j - 4) * 512]);
            }
        }
        bf16x8 af[2], bfr[8];
#pragma unroll
        for (int mt = 0; mt < 2; ++mt)
            af[mt] = *(const bf16x8*)&sQ[cur][(wm * 2 + mt) * 512 + lane * 8];
#pragma unroll
        for (int jt = 0; jt < 8; ++jt)
            bfr[jt] = *(const bf16x8*)&sK[cur][(wt * 8 + jt) * 512 + lane * 8];
#pragma unroll
        for (int mt = 0; mt < 2; ++mt)
#pragma unroll
            for (int jt = 0; jt < 8; ++jt)
                acc[mt][jt] = mfma16(af[mt], bfr[jt], acc[mt][jt]);
        if (kc < 15) {
            asm volatile("s_waitcnt vmcnt(0)" ::: "memory");
            __builtin_amdgcn_s_barrier();
            __builtin_amdgcn_sched_barrier(0);
        }
    }

    // ---------------- Phase 2: softmax + mask ----------------
    const float scale = 0.044194173824159216f;
#pragma unroll
    for (int i = 0; i < 2; ++i)
#pragma unroll
        for (int j = 0; j < 8; ++j) acc[i][j] *= scale;

    float rmax[2][4], rinv[2][4];
#pragma unroll
    for (int i = 0; i < 2; ++i)
#pragma unroll
        for (int r = 0; r < 4; ++r) {
            float v = -1e30f;
#pragma unroll
            for (int j = 0; j < 8; ++j) v = fmaxf(v, acc[i][j][r]);
            v = fmaxf(v, __shfl_xor(v, 1));
            v = fmaxf(v, __shfl_xor(v, 2));
            v = fmaxf(v, __shfl_xor(v, 4));
            v = fmaxf(v, __shfl_xor(v, 8));
            if (lr == 0) sStat[wm * 32 + i * 16 + lh * 4 + r][wt] = v;
        }
    __syncthreads();   // A
#pragma unroll
    for (int i = 0; i < 2; ++i)
#pragma unroll
        for (int r = 0; r < 4; ++r) {
            const int m = wm * 32 + i * 16 + lh * 4 + r;
            rmax[i][r] = fmaxf(sStat[m][0], sStat[m][1]);
        }
    __syncthreads();   // B
#pragma unroll
    for (int i = 0; i < 2; ++i)
#pragma unroll
        for (int r = 0; r < 4; ++r) {
            float s = 0.f;
#pragma unroll
            for (int j = 0; j < 8; ++j) {
                const float p = __expf(acc[i][j][r] - rmax[i][r]);
                acc[i][j][r] = p;
                s += p;
            }
            s += __shfl_xor(s, 1);
            s += __shfl_xor(s, 2);
            s += __shfl_xor(s, 4);
            s += __shfl_xor(s, 8);
            if (lr == 0) sStat[wm * 32 + i * 16 + lh * 4 + r][wt] = s;
        }
    __syncthreads();   // C

    // T14: prefetch phase-3 step-0 V tiles into sK[0] now; sync D drains them.
#pragma unroll
    for (int i = 0; i < 4; ++i) {
        const int nt = w * 4 + i;
        gload16(vb + ((size_t)(bd * 32 + nt) * 8 + 0) * 512 + lane * 8,
                &sK[0][nt * 512]);
    }

#pragma unroll
    for (int i = 0; i < 2; ++i)
#pragma unroll
        for (int r = 0; r < 4; ++r) {
            const int m = wm * 32 + i * 16 + lh * 4 + r;
            rinv[i][r] = 1.0f / (sStat[m][0] + sStat[m][1]);
        }

#pragma unroll
    for (int i = 0; i < 2; ++i)
#pragma unroll
        for (int r = 0; r < 4; ++r) {
            const int m_loc = wm * 32 + i * 16 + lh * 4 + r;
            const int ig = r0 + m_loc;
            float* orow = &outmat[(size_t)b_ * 4194304 +
                                  (size_t)(dd * 256 + ig) * 2048 + dd * 256];
#pragma unroll
            for (int j = 0; j < 8; ++j) {
                const int t = wt * 128 + j * 16 + lr;
                float a = acc[i][j][r] * rinv[i][r];
                const int d = (ig > t) ? (ig - t) : (t - ig);
                int ov = 512 - d * n; if (ov < 0) ov = 0;
                if (d == 0 || ((2 * ov >= 512) && (ov < 512))) a = 0.f;
                orow[t] = a;
                sP[((t >> 5) * 4 + (m_loc >> 4)) * 512 +
                   (((t & 31) >> 3) * 16 + (m_loc & 15)) * 8 + (t & 7)] = f2bf(a);
            }
        }
    __syncthreads();   // D: drains V prefetch (vmcnt) + sP writes (lgkm)

    // ---------------- Phase 3: out = P V (dbuf V, stage-early) ----------------
    f32x4 accB[2][8];
#pragma unroll
    for (int i = 0; i < 2; ++i)
#pragma unroll
        for (int j = 0; j < 8; ++j) acc[i][j] = (f32x4){0.f, 0.f, 0.f, 0.f};

#pragma unroll 1
    for (int step = 0; step < 8; ++step) {
        const int cur = step & 1;
        const int ns = step + 1;
#pragma unroll
        for (int i = 0; i < 4; ++i) {
            const int nt = w * 4 + i;
            gload16(vb + ((size_t)(bd * 32 + (ns >> 3) * 16 + nt) * 8 + (ns & 7)) * 512 +
                    lane * 8, &sK[cur ^ 1][nt * 512]);
        }
        bf16x8 af[2], bfr[8];
#pragma unroll
        for (int mt = 0; mt < 2; ++mt)
            af[mt] = *(const bf16x8*)&sP[(step * 4 + wm * 2 + mt) * 512 + lane * 8];
#pragma unroll
        for (int jt = 0; jt < 8; ++jt)
            bfr[jt] = *(const bf16x8*)&sK[cur][(wt * 8 + jt) * 512 + lane * 8];
#pragma unroll
        for (int mt = 0; mt < 2; ++mt)
#pragma unroll
            for (int jt = 0; jt < 8; ++jt)
                acc[mt][jt] = mfma16(af[mt], bfr[jt], acc[mt][jt]);
        asm volatile("s_waitcnt vmcnt(0)" ::: "memory");
        __builtin_amdgcn_s_barrier();
        __builtin_amdgcn_sched_barrier(0);
    }

#pragma unroll
    for (int i = 0; i < 2; ++i)
#pragma unroll
        for (int j = 0; j < 8; ++j) accB[i][j] = (f32x4){0.f, 0.f, 0.f, 0.f};

#pragma unroll 1
    for (int step = 8; step < 16; ++step) {
        const int cur = step & 1, tc = step & 7;
        if (step < 15) {
            const int ns = step + 1;
#pragma unroll
            for (int i = 0; i < 4; ++i) {
                const int nt = w * 4 + i;
                gload16(vb + ((size_t)(bd * 32 + 16 + nt) * 8 + (ns & 7)) * 512 +
                        lane * 8, &sK[cur ^ 1][nt * 512]);
            }
        }
        bf16x8 af[2], bfr[8];
#pragma unroll
        for (int mt = 0; mt < 2; ++mt)
            af[mt] = *(const bf16x8*)&sP[(tc * 4 + wm * 2 + mt) * 512 + lane * 8];
#pragma unroll
        for (int jt = 0; jt < 8; ++jt)
            bfr[jt] = *(const bf16x8*)&sK[cur][(wt * 8 + jt) * 512 + lane * 8];
#pragma unroll
        for (int mt = 0; mt < 2; ++mt)
#pragma unroll
            for (int jt = 0; jt < 8; ++jt)
                accB[mt][jt] = mfma16(af[mt], bfr[jt], accB[mt][jt]);
        if (step < 15) {
            asm volatile("s_waitcnt vmcnt(0)" ::: "memory");
            __builtin_amdgcn_s_barrier();
            __builtin_amdgcn_sched_barrier(0);
        }
    }

    // Fused epilogue: both nc halves.
#pragma unroll
    for (int mt = 0; mt < 2; ++mt)
#pragma unroll
        for (int jt = 0; jt < 8; ++jt) {
            const int ng = wt * 128 + jt * 16 + lr;
#pragma unroll
            for (int r = 0; r < 4; ++r) {
                const int m_loc = wm * 32 + mt * 16 + lh * 4 + r;
                float* orow = &out[((size_t)bd * 256 + r0 + m_loc) * 512];
                orow[ng] = acc[mt][jt][r];
                orow[256 + ng] = accB[mt][jt][r];
            }
        }
}

// ---------------------------------------------------------------------------
extern "C" void kernel_launch(void* const* d_in, const int* in_sizes, int n_in,
                              void* d_out, int out_size, void* d_ws, size_t ws_size,
                              hipStream_t stream) {
    (void)in_sizes; (void)n_in; (void)out_size; (void)ws_size;
    const float* x     = (const float*)d_in[0];
    const float* Wqkv  = (const float*)d_in[1];
    const float* bqkv  = (const float*)d_in[2];
    const int*   n_ptr = (const int*)d_in[3];

    float* out    = (float*)d_out;
    float* outmat = out + (size_t)16 * 2048 * 512;

    u16* xb = (u16*)d_ws;                 // 16,777,216
    u16* wb = xb + 16777216;              //    786,432
    u16* qb = wb + 786432;                // 16,777,216
    u16* kb = qb + 16777216;              // 16,777,216
    u16* vb = kb + 16777216;              // 16,777,216

    cast_bf16<<<8576, 256, 0, stream>>>(x, Wqkv, xb, wb);

    qkv_gemm<<<1536, 256, 0, stream>>>(xb, wb, bqkv, qb, kb, vb, outmat);

    attn_kernel<<<512, 256, 0, stream>>>(qb, kb, vb, n_ptr, out, outmat);
}